// Round 4
// baseline (177.445 us; speedup 1.0000x reference)
//
#include <hip/hip_runtime.h>

// Geometry fixed by setup_inputs: [16, 1, 352, 1216] fp32.
#define BATCH 16
#define HH    352
#define WW    1216
#define IMG   (HH * WW)
#define QPR   (WW / 4)       // 304 quads (float4 groups) per row
#define ROWS  4              // output rows per thread/strip
#define NROW  (ROWS + 2)     // rows loaded (incl. halo)
#define STRIPS (HH / ROWS)   // 88
#define BLOCK 320            // 5 waves; covers one full row (304 quads + 16 idle)
#define NWAVE (BLOCK / 64)

__device__ __forceinline__ float med3f(float a, float b, float c) {
#if defined(__has_builtin) && __has_builtin(__builtin_amdgcn_fmed3f)
    return __builtin_amdgcn_fmed3f(a, b, c);
#else
    return fmaxf(fminf(fmaxf(a, b), c), fminf(a, b));
#endif
}

// Expand a float4 center (cols c0..c0+3) to a 6-wide segment [c0-1..c0+4]
// using intra-wave shuffles for the halo columns; wave-edge lanes patch with
// an exec-masked scalar load. Zero-pads at image edges / invalid rows.
__device__ __forceinline__ void assemble6(float4 v, const float* __restrict__ r,
                                          bool hv, int c0, int lane, float o[6]) {
    float lft = __shfl_up(v.w, 1, 64);    // lane q-1's v.w == col c0-1
    float rgt = __shfl_down(v.x, 1, 64);  // lane q+1's v.x == col c0+4
    if (lane == 0)  lft = r[max(c0 - 1, 0)];
    if (lane == 63) rgt = r[min(c0 + 4, WW - 1)];
    o[0] = (hv && c0 > 0)      ? lft : 0.f;
    o[1] = hv ? v.x : 0.f;
    o[2] = hv ? v.y : 0.f;
    o[3] = hv ? v.z : 0.f;
    o[4] = hv ? v.w : 0.f;
    o[5] = (hv && c0 + 4 < WW) ? rgt : 0.f;
}

// contrast[i] = center - exact median3x3 for 4 pixels, from 3 row segments.
// Column sort3 + med3(max3(lo), med3(mid), min3(hi)) per pixel.
__device__ __forceinline__ void contrast4(const float rp[6], const float rc[6],
                                          const float rn[6], float c[4]) {
    float lo[6], mid[6], hi[6];
#pragma unroll
    for (int j = 0; j < 6; ++j) {
        float a = rp[j], b = rc[j], d = rn[j];
        float t0 = fminf(a, b), t1 = fmaxf(a, b);
        float t2 = fminf(t1, d);
        hi[j]  = fmaxf(t1, d);
        lo[j]  = fminf(t0, t2);
        mid[j] = fmaxf(t0, t2);
    }
#pragma unroll
    for (int i = 0; i < 4; ++i) {
        float mx = fmaxf(fmaxf(lo[i], lo[i + 1]), lo[i + 2]);
        float md = med3f(mid[i], mid[i + 1], mid[i + 2]);
        float mn = fminf(fminf(hi[i], hi[i + 1]), hi[i + 2]);
        c[i] = rc[i + 1] - med3f(mx, md, mn);
    }
}

__device__ __forceinline__ float waveRed(float v) {
#pragma unroll
    for (int o = 32; o > 0; o >>= 1) v += __shfl_down(v, o, 64);
    return v;
}

// Pass 1: per-image sums of {mask, mask*|pred_contrast|, mask*|target_contrast|}.
// __launch_bounds__(.,4): min 4 waves/EU -> 128-VGPR pressure budget, which is
// what allows the scheduler to keep the upfront float4 loads in flight (at the
// default 8-waves/EU target it serializes them into a 40-VGPR kernel).
__global__ __launch_bounds__(BLOCK, 4) void pass1(const float* __restrict__ pred,
                                                  const float* __restrict__ tgt,
                                                  const float* __restrict__ mask,
                                                  float* __restrict__ sums) {
    const int b  = blockIdx.y;
    const int r0 = blockIdx.x * ROWS;
    const int q  = threadIdx.x;
    const int c0 = q * 4;
    const int cc = min(c0, WW - 4);
    const int lane = threadIdx.x & 63;
    const bool qv = q < QPR;

    const float* pimg = pred + b * IMG;
    const float* timg = tgt  + b * IMG;
    const float* mimg = mask + b * IMG;

    // ---- Issue ALL float4 loads upfront (16 independent VMEM ops) ----
    float4 Pv[NROW], Tv[NROW], Mv[ROWS];
#pragma unroll
    for (int i = 0; i < NROW; ++i) {
        const int h = r0 - 1 + i;
        const int hc = ((unsigned)h < (unsigned)HH) ? h : 0;
        Pv[i] = *reinterpret_cast<const float4*>(pimg + hc * WW + cc);
        Tv[i] = *reinterpret_cast<const float4*>(timg + hc * WW + cc);
    }
#pragma unroll
    for (int i = 0; i < ROWS; ++i)
        Mv[i] = *reinterpret_cast<const float4*>(mimg + (r0 + i) * WW + cc);

    // ---- Assemble 6-wide segments (shfl halos), then compute ----
    float P[NROW][6], T[NROW][6];
#pragma unroll
    for (int i = 0; i < NROW; ++i) {
        const int h = r0 - 1 + i;
        const bool hv = ((unsigned)h < (unsigned)HH);
        const int hc = hv ? h : 0;
        assemble6(Pv[i], pimg + hc * WW, hv, c0, lane, P[i]);
        assemble6(Tv[i], timg + hc * WW, hv, c0, lane, T[i]);
    }

    float s_m = 0.f, s_p = 0.f, s_t = 0.f;
#pragma unroll
    for (int i = 0; i < ROWS; ++i) {
        float pc[4], tc[4];
        contrast4(P[i], P[i + 1], P[i + 2], pc);
        contrast4(T[i], T[i + 1], T[i + 2], tc);
        float mv[4] = {Mv[i].x, Mv[i].y, Mv[i].z, Mv[i].w};
#pragma unroll
        for (int k = 0; k < 4; ++k) {
            s_m += mv[k];
            s_p += mv[k] * fabsf(pc[k]);
            s_t += mv[k] * fabsf(tc[k]);
        }
    }
    if (!qv) { s_m = 0.f; s_p = 0.f; s_t = 0.f; }

    s_m = waveRed(s_m); s_p = waveRed(s_p); s_t = waveRed(s_t);

    __shared__ float red[3][NWAVE];
    const int wid = threadIdx.x >> 6;
    if (lane == 0) { red[0][wid] = s_m; red[1][wid] = s_p; red[2][wid] = s_t; }
    __syncthreads();
    if (threadIdx.x == 0) {
        float a0 = 0.f, a1 = 0.f, a2 = 0.f;
#pragma unroll
        for (int w = 0; w < NWAVE; ++w) { a0 += red[0][w]; a1 += red[1][w]; a2 += red[2][w]; }
        atomicAdd(&sums[b * 3 + 0], a0);
        atomicAdd(&sums[b * 3 + 1], a1);
        atomicAdd(&sums[b * 3 + 2], a2);
    }
}

// Pass 2: per-image sum of |pc/mean_pred - tc/mean_target|.
__global__ __launch_bounds__(BLOCK, 4) void pass2(const float* __restrict__ pred,
                                                  const float* __restrict__ tgt,
                                                  const float* __restrict__ sums,
                                                  float* __restrict__ acc) {
    const int b = blockIdx.y;
    const float denom  = sums[b * 3 + 0];
    const float inv_mp = denom / sums[b * 3 + 1];
    const float inv_mt = denom / sums[b * 3 + 2];

    const int r0 = blockIdx.x * ROWS;
    const int q  = threadIdx.x;
    const int c0 = q * 4;
    const int cc = min(c0, WW - 4);
    const int lane = threadIdx.x & 63;
    const bool qv = q < QPR;

    const float* pimg = pred + b * IMG;
    const float* timg = tgt  + b * IMG;

    float4 Pv[NROW], Tv[NROW];
#pragma unroll
    for (int i = 0; i < NROW; ++i) {
        const int h = r0 - 1 + i;
        const int hc = ((unsigned)h < (unsigned)HH) ? h : 0;
        Pv[i] = *reinterpret_cast<const float4*>(pimg + hc * WW + cc);
        Tv[i] = *reinterpret_cast<const float4*>(timg + hc * WW + cc);
    }

    float P[NROW][6], T[NROW][6];
#pragma unroll
    for (int i = 0; i < NROW; ++i) {
        const int h = r0 - 1 + i;
        const bool hv = ((unsigned)h < (unsigned)HH);
        const int hc = hv ? h : 0;
        assemble6(Pv[i], pimg + hc * WW, hv, c0, lane, P[i]);
        assemble6(Tv[i], timg + hc * WW, hv, c0, lane, T[i]);
    }

    float s = 0.f;
#pragma unroll
    for (int i = 0; i < ROWS; ++i) {
        float pc[4], tc[4];
        contrast4(P[i], P[i + 1], P[i + 2], pc);
        contrast4(T[i], T[i + 1], T[i + 2], tc);
#pragma unroll
        for (int k = 0; k < 4; ++k)
            s += fabsf(pc[k] * inv_mp - tc[k] * inv_mt);
    }
    if (!qv) s = 0.f;

    s = waveRed(s);

    __shared__ float red[NWAVE];
    const int wid = threadIdx.x >> 6;
    if (lane == 0) red[wid] = s;
    __syncthreads();
    if (threadIdx.x == 0) {
        float a = 0.f;
#pragma unroll
        for (int w = 0; w < NWAVE; ++w) a += red[w];
        atomicAdd(&acc[b], a);
    }
}

__global__ void finalize(const float* __restrict__ sums,
                         const float* __restrict__ acc,
                         float* __restrict__ out) {
    float tm = 0.f, ta = 0.f;
    for (int b = 0; b < BATCH; ++b) { tm += sums[b * 3 + 0]; ta += acc[b]; }
    out[0] = ta / tm;
}

extern "C" void kernel_launch(void* const* d_in, const int* in_sizes, int n_in,
                              void* d_out, int out_size, void* d_ws, size_t ws_size,
                              hipStream_t stream) {
    const float* pred = (const float*)d_in[0];
    const float* tgt  = (const float*)d_in[1];
    const float* mask = (const float*)d_in[2];
    float* out = (float*)d_out;
    float* ws  = (float*)d_ws;  // [0..47] per-image {Sm,Sp,St}; [48..63] per-image loss acc

    hipMemsetAsync(d_ws, 0, 64 * sizeof(float), stream);

    dim3 grid(STRIPS, BATCH), blk(BLOCK);
    pass1<<<grid, blk, 0, stream>>>(pred, tgt, mask, ws);
    pass2<<<grid, blk, 0, stream>>>(pred, tgt, ws, ws + 48);
    finalize<<<1, 1, 0, stream>>>(ws, ws + 48, out);
}

// Round 5
// 176.507 us; speedup vs baseline: 1.0053x; 1.0053x over previous
//
#include <hip/hip_runtime.h>

// Geometry fixed by setup_inputs: [16, 1, 352, 1216] fp32.
#define BATCH 16
#define HH    352
#define WW    1216
#define IMG   (HH * WW)
#define QPR   (WW / 4)       // 304 quads per row
#define ROWS  4              // output rows per strip
#define NROW  (ROWS + 2)     // rows staged (incl. halo)
#define STRIPS (HH / ROWS)   // 88
#define BLOCK 320            // 5 waves: 304 compute threads + staging helpers
#define NWAVE (BLOCK / 64)
#define ROWB  (WW * 4)       // bytes per row (4864)
#define TILEF (NROW * WW)    // floats per tensor tile

typedef unsigned int u32;

__device__ __forceinline__ float med3f(float a, float b, float c) {
#if defined(__has_builtin) && __has_builtin(__builtin_amdgcn_fmed3f)
    return __builtin_amdgcn_fmed3f(a, b, c);
#else
    return fmaxf(fminf(fmaxf(a, b), c), fminf(a, b));
#endif
}

// Stage NROW rows (global rows r0-1 .. r0+ROWS) of one tensor into an LDS
// tile as a single flat copy via global_load_lds DMA (zero VGPR cost, full
// MLP in hardware). Out-of-image halo rows are zero-filled by vector stores.
__device__ __forceinline__ void stage_tile(const float* __restrict__ g,
                                           float* tile, int r0, int wid,
                                           int lane, int q) {
    int rlo = 0, rhi = 0;
    if (r0 == 0) {
        rlo = 1;
        if (q < QPR) *reinterpret_cast<float4*>(&tile[q * 4]) = make_float4(0.f, 0.f, 0.f, 0.f);
    }
    if (r0 + ROWS == HH) {
        rhi = 1;
        if (q < QPR) *reinterpret_cast<float4*>(&tile[(NROW - 1) * WW + q * 4]) = make_float4(0.f, 0.f, 0.f, 0.f);
    }
    const int nbytes = (NROW - rlo - rhi) * ROWB;
    const char* gsrc = reinterpret_cast<const char*>(g + (r0 - 1 + rlo) * WW);
    char* ldst = reinterpret_cast<char*>(tile + rlo * WW);
    const int chunks = (nbytes + 1023) >> 10;   // 1 KB per wave-instruction
    for (int c = wid; c < chunks; c += NWAVE) {
        const int off = (c << 10) + lane * 16;
        if (off < nbytes) {
#if defined(__has_builtin) && __has_builtin(__builtin_amdgcn_global_load_lds)
            __builtin_amdgcn_global_load_lds(
                (const __attribute__((address_space(1))) u32*)(gsrc + off),
                (__attribute__((address_space(3))) u32*)(ldst + (c << 10)),
                16, 0, 0);
#else
            *reinterpret_cast<float4*>(ldst + off) =
                *reinterpret_cast<const float4*>(gsrc + off);
#endif
        }
    }
}

// Read the 6-wide segment [cq-1 .. cq+4] of LDS tile row r via three aligned
// ds_read_b128 (lane stride 16 B -> conflict-free). lz/rz zero the image-edge
// halo columns.
__device__ __forceinline__ void seg6(const float* tile, int r, int cq,
                                     bool lz, bool rz, float o[6]) {
    const float* p = tile + r * WW + cq;
    float4 L = *reinterpret_cast<const float4*>(p - 4);
    float4 C = *reinterpret_cast<const float4*>(p);
    float4 R = *reinterpret_cast<const float4*>(p + 4);
    o[0] = lz ? 0.f : L.w;
    o[1] = C.x; o[2] = C.y; o[3] = C.z; o[4] = C.w;
    o[5] = rz ? 0.f : R.x;
}

// contrast[i] = center - exact median3x3 for 4 pixels, from 3 row segments.
__device__ __forceinline__ void contrast4(const float rp[6], const float rc[6],
                                          const float rn[6], float c[4]) {
    float lo[6], mid[6], hi[6];
#pragma unroll
    for (int j = 0; j < 6; ++j) {
        float a = rp[j], b = rc[j], d = rn[j];
        float t0 = fminf(a, b), t1 = fmaxf(a, b);
        float t2 = fminf(t1, d);
        hi[j]  = fmaxf(t1, d);
        lo[j]  = fminf(t0, t2);
        mid[j] = fmaxf(t0, t2);
    }
#pragma unroll
    for (int i = 0; i < 4; ++i) {
        float mx = fmaxf(fmaxf(lo[i], lo[i + 1]), lo[i + 2]);
        float md = med3f(mid[i], mid[i + 1], mid[i + 2]);
        float mn = fminf(fminf(hi[i], hi[i + 1]), hi[i + 2]);
        c[i] = rc[i + 1] - med3f(mx, md, mn);
    }
}

__device__ __forceinline__ float waveRed(float v) {
#pragma unroll
    for (int o = 32; o > 0; o >>= 1) v += __shfl_down(v, o, 64);
    return v;
}

// Pass 1: per-image sums of {mask, mask*|pred_contrast|, mask*|target_contrast|}.
__global__ __launch_bounds__(BLOCK, 2) void pass1(const float* __restrict__ pred,
                                                  const float* __restrict__ tgt,
                                                  const float* __restrict__ mask,
                                                  float* __restrict__ sums) {
    __shared__ __align__(16) float lds[4 + 2 * TILEF + 8];
    float* Pt = lds + 4;
    float* Tt = Pt + TILEF;

    const int b  = blockIdx.y;
    const int r0 = blockIdx.x * ROWS;
    const int q  = threadIdx.x;
    const int lane = threadIdx.x & 63, wid = threadIdx.x >> 6;
    const bool qv = q < QPR;
    const int cq = min(q * 4, WW - 4);
    const bool lz = (cq == 0);
    const bool rz = (cq + 4 >= WW);

    const float* pimg = pred + b * IMG;
    const float* timg = tgt  + b * IMG;
    const float* mimg = mask + b * IMG;

    // DMA both tiles (all instructions issued before any wait).
    stage_tile(pimg, Pt, r0, wid, lane, q);
    stage_tile(timg, Tt, r0, wid, lane, q);

    // Mask rows: direct coalesced global loads (independent of the DMA).
    float4 Mv[ROWS];
#pragma unroll
    for (int i = 0; i < ROWS; ++i)
        Mv[i] = *reinterpret_cast<const float4*>(mimg + (r0 + i) * WW + cq);

    __syncthreads();   // drains vmcnt (global_load_lds) + lgkmcnt

    // Load all row segments once from LDS, reuse across the 3 windows each.
    float P[NROW][6], T[NROW][6];
#pragma unroll
    for (int r = 0; r < NROW; ++r) {
        seg6(Pt, r, cq, lz, rz, P[r]);
        seg6(Tt, r, cq, lz, rz, T[r]);
    }

    float s_m = 0.f, s_p = 0.f, s_t = 0.f;
#pragma unroll
    for (int i = 0; i < ROWS; ++i) {
        float pc[4], tc[4];
        contrast4(P[i], P[i + 1], P[i + 2], pc);
        contrast4(T[i], T[i + 1], T[i + 2], tc);
        float mv[4] = {Mv[i].x, Mv[i].y, Mv[i].z, Mv[i].w};
#pragma unroll
        for (int k = 0; k < 4; ++k) {
            s_m += mv[k];
            s_p += mv[k] * fabsf(pc[k]);
            s_t += mv[k] * fabsf(tc[k]);
        }
    }
    if (!qv) { s_m = 0.f; s_p = 0.f; s_t = 0.f; }

    s_m = waveRed(s_m); s_p = waveRed(s_p); s_t = waveRed(s_t);

    __shared__ float red[3][NWAVE];
    if (lane == 0) { red[0][wid] = s_m; red[1][wid] = s_p; red[2][wid] = s_t; }
    __syncthreads();
    if (threadIdx.x == 0) {
        float a0 = 0.f, a1 = 0.f, a2 = 0.f;
#pragma unroll
        for (int w = 0; w < NWAVE; ++w) { a0 += red[0][w]; a1 += red[1][w]; a2 += red[2][w]; }
        atomicAdd(&sums[b * 3 + 0], a0);
        atomicAdd(&sums[b * 3 + 1], a1);
        atomicAdd(&sums[b * 3 + 2], a2);
    }
}

// Pass 2: per-image sum of |pc/mean_pred - tc/mean_target|.
__global__ __launch_bounds__(BLOCK, 2) void pass2(const float* __restrict__ pred,
                                                  const float* __restrict__ tgt,
                                                  const float* __restrict__ sums,
                                                  float* __restrict__ acc) {
    __shared__ __align__(16) float lds[4 + 2 * TILEF + 8];
    float* Pt = lds + 4;
    float* Tt = Pt + TILEF;

    const int b = blockIdx.y;
    const float denom  = sums[b * 3 + 0];
    const float inv_mp = denom / sums[b * 3 + 1];
    const float inv_mt = denom / sums[b * 3 + 2];

    const int r0 = blockIdx.x * ROWS;
    const int q  = threadIdx.x;
    const int lane = threadIdx.x & 63, wid = threadIdx.x >> 6;
    const bool qv = q < QPR;
    const int cq = min(q * 4, WW - 4);
    const bool lz = (cq == 0);
    const bool rz = (cq + 4 >= WW);

    const float* pimg = pred + b * IMG;
    const float* timg = tgt  + b * IMG;

    stage_tile(pimg, Pt, r0, wid, lane, q);
    stage_tile(timg, Tt, r0, wid, lane, q);

    __syncthreads();

    float P[NROW][6], T[NROW][6];
#pragma unroll
    for (int r = 0; r < NROW; ++r) {
        seg6(Pt, r, cq, lz, rz, P[r]);
        seg6(Tt, r, cq, lz, rz, T[r]);
    }

    float s = 0.f;
#pragma unroll
    for (int i = 0; i < ROWS; ++i) {
        float pc[4], tc[4];
        contrast4(P[i], P[i + 1], P[i + 2], pc);
        contrast4(T[i], T[i + 1], T[i + 2], tc);
#pragma unroll
        for (int k = 0; k < 4; ++k)
            s += fabsf(pc[k] * inv_mp - tc[k] * inv_mt);
    }
    if (!qv) s = 0.f;

    s = waveRed(s);

    __shared__ float red[NWAVE];
    if (lane == 0) red[wid] = s;
    __syncthreads();
    if (threadIdx.x == 0) {
        float a = 0.f;
#pragma unroll
        for (int w = 0; w < NWAVE; ++w) a += red[w];
        atomicAdd(&acc[b], a);
    }
}

__global__ void finalize(const float* __restrict__ sums,
                         const float* __restrict__ acc,
                         float* __restrict__ out) {
    float tm = 0.f, ta = 0.f;
    for (int b = 0; b < BATCH; ++b) { tm += sums[b * 3 + 0]; ta += acc[b]; }
    out[0] = ta / tm;
}

extern "C" void kernel_launch(void* const* d_in, const int* in_sizes, int n_in,
                              void* d_out, int out_size, void* d_ws, size_t ws_size,
                              hipStream_t stream) {
    const float* pred = (const float*)d_in[0];
    const float* tgt  = (const float*)d_in[1];
    const float* mask = (const float*)d_in[2];
    float* out = (float*)d_out;
    float* ws  = (float*)d_ws;  // [0..47] per-image {Sm,Sp,St}; [48..63] per-image loss acc

    hipMemsetAsync(d_ws, 0, 64 * sizeof(float), stream);

    dim3 grid(STRIPS, BATCH), blk(BLOCK);
    pass1<<<grid, blk, 0, stream>>>(pred, tgt, mask, ws);
    pass2<<<grid, blk, 0, stream>>>(pred, tgt, ws, ws + 48);
    finalize<<<1, 1, 0, stream>>>(ws, ws + 48, out);
}